// Round 10
// baseline (49.005 us; speedup 1.0000x reference)
//
#include <hip/hip_runtime.h>
#include <stdint.h>

#define BB 4
#define NN 2048
#define F_IN 128
#define F_OUT 256
#define NH 4
#define HD 64

typedef float f32x4 __attribute__((ext_vector_type(4)));
typedef float f32x2 __attribute__((ext_vector_type(2)));
typedef short s16x8 __attribute__((ext_vector_type(8)));
typedef int i32x4 __attribute__((ext_vector_type(4)));
typedef unsigned long long u64;
typedef unsigned short u16;

#define LOG2E 1.4426950408889634f

__device__ __forceinline__ u16 f32_to_bf16_rtn(float f) {
    union { float f; uint32_t u; } v; v.f = f;
    uint32_t u = v.u;
    u += 0x7fffu + ((u >> 16) & 1u);
    return (u16)(u >> 16);
}

__device__ __forceinline__ float exp2_fast(float x) {
#if __has_builtin(__builtin_amdgcn_exp2f)
    return __builtin_amdgcn_exp2f(x);
#else
    return exp2f(x);
#endif
}

__device__ __forceinline__ int sbfe1(uint32_t v, int k) {
#if __has_builtin(__builtin_amdgcn_sbfe)
    return __builtin_amdgcn_sbfe((int)v, k, 1);   // bit k sign-extended: 0 or -1
#else
    return ((int32_t)(v << (31 - k))) >> 31;
#endif
}

// K01: fused adj-pack (HBM-streaming, 8-deep load batching) + projection.
// Blocks 0..511 = proj (16-row tiles); 512..2559 = pack.
__global__ __launch_bounds__(256) void k01(
    const int* __restrict__ adj, const float* __restrict__ x,
    const float* __restrict__ W, const float* __restrict__ a_l,
    const float* __restrict__ a_r, u64* __restrict__ abits,
    u16* __restrict__ hB, float* __restrict__ el, f32x2* __restrict__ er12)
{
    const int t = threadIdx.x;

    __shared__ __align__(16) float xs[16][F_IN];    // 8 KB
    __shared__ __align__(16) float red[4 * 64 * 20]; // 20 KB (reused for l then r)

    if (blockIdx.x >= 512) {
        // ---- pack adj -> bitmask u64[B*N][32]; 8 loads in flight per group ----
        const int wid = ((blockIdx.x - 512) << 2) | (t >> 6);
        const int lane = t & 63;
        const int* rowp = adj + (size_t)wid * NN;
        u64 mym = 0;
        for (int g = 0; g < 4; ++g) {
            int v[8];
#pragma unroll
            for (int u = 0; u < 8; ++u) v[u] = rowp[(g * 8 + u) * 64 + lane];
#pragma unroll
            for (int u = 0; u < 8; ++u) {
                u64 m = __ballot(v[u] != 0);
                if (lane == g * 8 + u) mym = m;
            }
        }
        if (lane < 32) abits[(size_t)wid * 32 + lane] = mym;
        return;
    }

    // ---- projection: h = x @ W^T (fp32) ----
    const int b = blockIdx.x >> 7;
    const int n0 = (blockIdx.x & 127) * 16;

    {
        const f32x4* src = (const f32x4*)(x + ((size_t)b * NN + n0) * F_IN);
        f32x4* dst = (f32x4*)&xs[0][0];
        dst[t] = src[t];
        dst[t + 256] = src[t + 256];
    }
    __syncthreads();

    float acc[16];
#pragma unroll
    for (int n = 0; n < 16; ++n) acc[n] = 0.f;

    const float* wrow = W + (size_t)t * F_IN;
#pragma unroll 2
    for (int k0 = 0; k0 < F_IN; k0 += 8) {
        f32x4 w0 = *(const f32x4*)(wrow + k0);
        f32x4 w1 = *(const f32x4*)(wrow + k0 + 4);
#pragma unroll
        for (int n = 0; n < 16; ++n) {
            f32x4 xa = *(const f32x4*)&xs[n][k0];
            f32x4 xb = *(const f32x4*)&xs[n][k0 + 4];
            float s = acc[n];
            s = fmaf(xa[0], w0[0], s); s = fmaf(xa[1], w0[1], s);
            s = fmaf(xa[2], w0[2], s); s = fmaf(xa[3], w0[3], s);
            s = fmaf(xb[0], w1[0], s); s = fmaf(xb[1], w1[1], s);
            s = fmaf(xb[2], w1[2], s); s = fmaf(xb[3], w1[3], s);
            acc[n] = s;
        }
    }

    const int w = t >> 6, lane = t & 63;
    const float al = a_l[t];
    const float ar = a_r[t];
    const int n_ = lane & 15, og = lane >> 4;
    float sl, sr;
    // l pass
    {
        float* rp = &red[((size_t)w * 64 + lane) * 20];
#pragma unroll
        for (int q = 0; q < 4; ++q) {
            f32x4 v;
#pragma unroll
            for (int e = 0; e < 4; ++e) v[e] = acc[q * 4 + e] * al;
            *(f32x4*)(rp + q * 4) = v;
        }
    }
    __syncthreads();
    {
        float s = 0.f;
#pragma unroll
        for (int oo = 0; oo < 16; ++oo)
            s += red[((size_t)w * 64 + og + 4 * oo) * 20 + n_];
        s += __shfl_xor(s, 16, 64); s += __shfl_xor(s, 32, 64);
        sl = s;
    }
    __syncthreads();
    // r pass (reuse buffer)
    {
        float* rp = &red[((size_t)w * 64 + lane) * 20];
#pragma unroll
        for (int q = 0; q < 4; ++q) {
            f32x4 v;
#pragma unroll
            for (int e = 0; e < 4; ++e) v[e] = acc[q * 4 + e] * ar;
            *(f32x4*)(rp + q * 4) = v;
        }
    }
    __syncthreads();
    {
        float s = 0.f;
#pragma unroll
        for (int oo = 0; oo < 16; ++oo)
            s += red[((size_t)w * 64 + og + 4 * oo) * 20 + n_];
        s += __shfl_xor(s, 16, 64); s += __shfl_xor(s, 32, 64);
        sr = s;
    }
    if (lane < 16) {
        el[((size_t)b * NH + w) * NN + n0 + lane] = sl * LOG2E;
        float sre = sr * LOG2E;
        f32x2 v2; v2[0] = exp2_fast(sre); v2[1] = exp2_fast(0.2f * sre);
        er12[((size_t)b * NH + w) * NN + n0 + lane] = v2;
    }

    // B-fragment layout store: hB[b][jt32][head][cb][lane64][8] (bf16)
    const int dcol = t & 15, cb = (t >> 4) & 3;
    const int jt32 = n0 >> 5;
    const int lb = dcol + ((n0 >> 3) & 2) * 16;
    u16* hb = hB + ((((size_t)b * 64 + jt32) * 4 + w) * 4 + cb) * 512 + (size_t)lb * 8;
    s16x8 pk0, pk1;
#pragma unroll
    for (int n = 0; n < 8; ++n) pk0[n] = (short)f32_to_bf16_rtn(acc[n]);
#pragma unroll
    for (int n = 0; n < 8; ++n) pk1[n] = (short)f32_to_bf16_rtn(acc[n + 8]);
    *(s16x8*)hb         = pk0;
    *(s16x8*)(hb + 128) = pk1;
}

// K2: fused masked softmax + aggregation.
// er12 + mask words staged in LDS once per block -> the ONLY global stream in
// the loop is the 4 dist-1 double-buffered B-frag loads (clean vmcnt FIFO).
// launch_bounds(256,4): ~120 VGPR target, 16 waves/CU.
#define MSTRIDE 68   // mask LDS row stride (u32): 68%32=4 -> 2-way banks (free)

__global__ __launch_bounds__(256, 4) void k2_attn(
    const uint32_t* __restrict__ abits32, const u16* __restrict__ hB,
    const float* __restrict__ el, const f32x2* __restrict__ er12,
    float* __restrict__ out)
{
    __shared__ __align__(16) char smem[33792];   // max(er 16K + mask 8.7K, racc 33K)
    float*    er_lds   = (float*)smem;           // [2048][2] floats
    uint32_t* mask_lds = (uint32_t*)(smem + 16384); // [32][MSTRIDE]
    float*    racc     = (float*)smem;           // alias (after barrier)

    const int t = threadIdx.x;
    const int jq = t >> 6, l = t & 63;
    int bid = blockIdx.x;
    bid = (bid & 7) * 128 + (bid >> 3);   // XCD swizzle (1024 % 8 == 0)
    const int b = bid >> 8;
    const int w = (bid >> 6) & 3;         // head
    const int i0 = (bid & 63) * 32;
    const int r = l & 15;                 // A row / D col
    const int kb = l >> 4;                // k-slice 0..3
    const int ks = kb * 8;
    const int irow0 = i0 + r, irow1 = irow0 + 16;

    // ---- stage er12 (16 KB) + masks (8 KB -> padded rows) into LDS ----
    {
        const f32x4* gsrc = (const f32x4*)(er12 + (size_t)(b * NH + w) * NN);
        f32x4* edst = (f32x4*)er_lds;
#pragma unroll
        for (int p = 0; p < 4; ++p) edst[t + p * 256] = gsrc[t + p * 256];
        const i32x4* msrc = (const i32x4*)(abits32 + ((size_t)b * NN + i0) * 64);
        i32x4 mv0 = msrc[t * 2];
        i32x4 mv1 = msrc[t * 2 + 1];
        const int mrow = t >> 3, mc = (t & 7) * 8;
        *(i32x4*)&mask_lds[mrow * MSTRIDE + mc]     = mv0;
        *(i32x4*)&mask_lds[mrow * MSTRIDE + mc + 4] = mv1;
    }

    const u16* hbp = hB + ((((size_t)b * 64 + jq * 16) * 4 + w) * 4) * 512 + (size_t)l * 8;
    const float eli0 = el[((size_t)b * NH + w) * NN + irow0];
    const float eli1 = el[((size_t)b * NH + w) * NN + irow1];
    const float E1i0 = exp2_fast(eli0), E2i0 = exp2_fast(0.2f * eli0);
    const float E1i1 = exp2_fast(eli1), E2i1 = exp2_fast(0.2f * eli1);

    f32x4 a00 = {0.f,0.f,0.f,0.f}, a01 = a00, a02 = a00, a03 = a00, as0 = a00;
    f32x4 a10 = a00, a11 = a00, a12 = a00, a13 = a00, as1 = a00;
    s16x8 ones;
#pragma unroll
    for (int k = 0; k < 8; ++k) ones[k] = (short)0x3F80;   // bf16 1.0

    // prologue: iter-0 B-frags
    s16x8 b0c = *(const s16x8*)(hbp + 0 * 512);
    s16x8 b1c = *(const s16x8*)(hbp + 1 * 512);
    s16x8 b2c = *(const s16x8*)(hbp + 2 * 512);
    s16x8 b3c = *(const s16x8*)(hbp + 3 * 512);
    __syncthreads();   // staging complete

#define MFMA_BF16 __builtin_amdgcn_mfma_f32_16x16x32_bf16
#define BODY(IT, PF)                                                          \
    {                                                                         \
        const int itv = (IT);                                                 \
        const int jb2 = (jq * 512 + itv * 32 + ks) * 2;                       \
        f32x4 e0 = *(const f32x4*)(er_lds + jb2);                             \
        f32x4 e1 = *(const f32x4*)(er_lds + jb2 + 4);                         \
        f32x4 e2 = *(const f32x4*)(er_lds + jb2 + 8);                         \
        f32x4 e3 = *(const f32x4*)(er_lds + jb2 + 12);                        \
        uint32_t w2a = mask_lds[r * MSTRIDE + jq * 16 + itv] >> ks;           \
        uint32_t w2b = mask_lds[(16 + r) * MSTRIDE + jq * 16 + itv] >> ks;    \
        s16x8 b0n, b1n, b2n, b3n;                                             \
        if (PF) {                                                             \
            const u16* hp_ = hbp + (size_t)(itv + 1) * 8192;                  \
            b0n = *(const s16x8*)(hp_ + 0 * 512);                             \
            b1n = *(const s16x8*)(hp_ + 1 * 512);                             \
            b2n = *(const s16x8*)(hp_ + 2 * 512);                             \
            b3n = *(const s16x8*)(hp_ + 3 * 512);                             \
        }                                                                     \
        __builtin_amdgcn_sched_barrier(0);                                    \
        union { s16x8 v; uint32_t u[4]; } afa, afb;                           \
        _Pragma("unroll")                                                     \
        for (int kk = 0; kk < 4; ++kk) {                                      \
            f32x4 ev = (kk == 0) ? e0 : ((kk == 1) ? e1 : ((kk == 2) ? e2 : e3)); \
            float t00 = E1i0 * ev[0], m00 = E2i0 * ev[1];                     \
            float t01 = E1i0 * ev[2], m01 = E2i0 * ev[3];                     \
            float t10 = E1i1 * ev[0], m10 = E2i1 * ev[1];                     \
            float t11 = E1i1 * ev[2], m11 = E2i1 * ev[3];                     \
            float p00 = (t00 >= 1.0f) ? t00 : m00;                            \
            float p01 = (t01 >= 1.0f) ? t01 : m01;                            \
            float p10 = (t10 >= 1.0f) ? t10 : m10;                            \
            float p11 = (t11 >= 1.0f) ? t11 : m11;                            \
            union { float f; uint32_t u; } c00, c01, c10, c11;                \
            c00.f = p00; c01.f = p01; c10.f = p10; c11.f = p11;               \
            uint32_t q00 = c00.u & (uint32_t)sbfe1(w2a, 2 * kk);              \
            uint32_t q01 = c01.u & (uint32_t)sbfe1(w2a, 2 * kk + 1);          \
            uint32_t q10 = c10.u & (uint32_t)sbfe1(w2b, 2 * kk);              \
            uint32_t q11 = c11.u & (uint32_t)sbfe1(w2b, 2 * kk + 1);          \
            afa.u[kk] = __builtin_amdgcn_perm(q01, q00, 0x07060302);          \
            afb.u[kk] = __builtin_amdgcn_perm(q11, q10, 0x07060302);          \
        }                                                                     \
        a00 = MFMA_BF16(afa.v, b0c, a00, 0, 0, 0);                            \
        a01 = MFMA_BF16(afa.v, b1c, a01, 0, 0, 0);                            \
        a02 = MFMA_BF16(afa.v, b2c, a02, 0, 0, 0);                            \
        a03 = MFMA_BF16(afa.v, b3c, a03, 0, 0, 0);                            \
        as0 = MFMA_BF16(afa.v, ones, as0, 0, 0, 0);                           \
        a10 = MFMA_BF16(afb.v, b0c, a10, 0, 0, 0);                            \
        a11 = MFMA_BF16(afb.v, b1c, a11, 0, 0, 0);                            \
        a12 = MFMA_BF16(afb.v, b2c, a12, 0, 0, 0);                            \
        a13 = MFMA_BF16(afb.v, b3c, a13, 0, 0, 0);                            \
        as1 = MFMA_BF16(afb.v, ones, as1, 0, 0, 0);                           \
        if (PF) { b0c = b0n; b1c = b1n; b2c = b2n; b3c = b3n; }               \
    }

    for (int g = 0; g < 3; ++g) {
#pragma unroll
        for (int s = 0; s < 4; ++s) BODY(g * 4 + s, 1);
    }
    BODY(12, 1); BODY(13, 1); BODY(14, 1); BODY(15, 0);

    // ---- cross-jq reduce through LDS (racc aliases er/mask region) ----
    __syncthreads();   // all waves done reading er_lds/mask_lds
    if (jq > 0) {
        float* p = &racc[((jq - 1) * 64 + l) * 44];
        *(f32x4*)(p +  0) = a00; *(f32x4*)(p +  4) = a01;
        *(f32x4*)(p +  8) = a02; *(f32x4*)(p + 12) = a03;
        *(f32x4*)(p + 16) = as0;
        *(f32x4*)(p + 20) = a10; *(f32x4*)(p + 24) = a11;
        *(f32x4*)(p + 28) = a12; *(f32x4*)(p + 32) = a13;
        *(f32x4*)(p + 36) = as1;
    }
    __syncthreads();
    if (jq == 0) {
#pragma unroll
        for (int s = 0; s < 3; ++s) {
            const float* p = &racc[(s * 64 + l) * 44];
            a00 += *(const f32x4*)(p +  0); a01 += *(const f32x4*)(p +  4);
            a02 += *(const f32x4*)(p +  8); a03 += *(const f32x4*)(p + 12);
            as0 += *(const f32x4*)(p + 16);
            a10 += *(const f32x4*)(p + 20); a11 += *(const f32x4*)(p + 24);
            a12 += *(const f32x4*)(p + 28); a13 += *(const f32x4*)(p + 32);
            as1 += *(const f32x4*)(p + 36);
        }

        float* op = out + ((size_t)b * NN + i0) * F_OUT + w * HD;
#pragma unroll
        for (int q = 0; q < 4; ++q) {
            const int row0 = kb * 4 + q;
            float inv0 = 1.0f / as0[q];
            op[(size_t)row0 * F_OUT +  0 + r] = a00[q] * inv0;
            op[(size_t)row0 * F_OUT + 16 + r] = a01[q] * inv0;
            op[(size_t)row0 * F_OUT + 32 + r] = a02[q] * inv0;
            op[(size_t)row0 * F_OUT + 48 + r] = a03[q] * inv0;
            const int row1 = 16 + kb * 4 + q;
            float inv1 = 1.0f / as1[q];
            op[(size_t)row1 * F_OUT +  0 + r] = a10[q] * inv1;
            op[(size_t)row1 * F_OUT + 16 + r] = a11[q] * inv1;
            op[(size_t)row1 * F_OUT + 32 + r] = a12[q] * inv1;
            op[(size_t)row1 * F_OUT + 48 + r] = a13[q] * inv1;
        }
    }
}

extern "C" void kernel_launch(void* const* d_in, const int* in_sizes, int n_in,
                              void* d_out, int out_size, void* d_ws, size_t ws_size,
                              hipStream_t stream) {
    const float* x   = (const float*)d_in[0];
    const int*   adj = (const int*)d_in[1];
    const float* W   = (const float*)d_in[2];
    const float* a_l = (const float*)d_in[3];
    const float* a_r = (const float*)d_in[4];
    float* out = (float*)d_out;

    char* ws = (char*)d_ws;
    u16*   hB    = (u16*)ws;                                   // 4 MB
    u64*   abits = (u64*)(ws + (size_t)BB * F_OUT * NN * 2);   // 2 MB
    float* el    = (float*)(ws + (size_t)BB * F_OUT * NN * 2 + (size_t)BB * NN * 32 * 8);
    f32x2* er12  = (f32x2*)(el + (size_t)BB * NH * NN);

    k01<<<512 + BB * NN / 4, 256, 0, stream>>>(adj, x, W, a_l, a_r, abits, hB, el, er12);
    k2_attn<<<BB * NH * (NN / 32), 256, 0, stream>>>((const uint32_t*)abits, hB, el, er12, out);
}

// Round 11
// 46.195 us; speedup vs baseline: 1.0608x; 1.0608x over previous
//
#include <hip/hip_runtime.h>
#include <stdint.h>

#define BB 4
#define NN 2048
#define F_IN 128
#define F_OUT 256
#define NH 4
#define HD 64

typedef float f32x4 __attribute__((ext_vector_type(4)));
typedef float f32x2 __attribute__((ext_vector_type(2)));
typedef short s16x8 __attribute__((ext_vector_type(8)));
typedef int i32x4 __attribute__((ext_vector_type(4)));
typedef unsigned long long u64;
typedef unsigned short u16;

#define LOG2E 1.4426950408889634f

__device__ __forceinline__ u16 f32_to_bf16_rtn(float f) {
    union { float f; uint32_t u; } v; v.f = f;
    uint32_t u = v.u;
    u += 0x7fffu + ((u >> 16) & 1u);
    return (u16)(u >> 16);
}

__device__ __forceinline__ float exp2_fast(float x) {
#if __has_builtin(__builtin_amdgcn_exp2f)
    return __builtin_amdgcn_exp2f(x);
#else
    return exp2f(x);
#endif
}

__device__ __forceinline__ int sbfe1(uint32_t v, int k) {
#if __has_builtin(__builtin_amdgcn_sbfe)
    return __builtin_amdgcn_sbfe((int)v, k, 1);   // bit k sign-extended: 0 or -1
#else
    return ((int32_t)(v << (31 - k))) >> 31;
#endif
}

// K01: fused adj-pack (HBM-streaming, nt loads, 8-deep batching) + projection.
// Blocks 0..511 = proj (16-row tiles); 512..2559 = pack.
// LDS 20 KB (x-tile aliased into reduce buffer) -> 8 blocks/CU.
__global__ __launch_bounds__(256) void k01(
    const int* __restrict__ adj, const float* __restrict__ x,
    const float* __restrict__ W, const float* __restrict__ a_l,
    const float* __restrict__ a_r, u64* __restrict__ abits,
    u16* __restrict__ hB, float* __restrict__ el, f32x2* __restrict__ er12)
{
    const int t = threadIdx.x;

    __shared__ __align__(16) float red[4 * 64 * 20];   // 20 KB; xs aliases front 8 KB
    float (*xs)[F_IN] = (float(*)[F_IN])red;

    if (blockIdx.x >= 512) {
        // ---- pack adj -> bitmask u64[B*N][32]; nt loads, 8 in flight ----
        const int wid = ((blockIdx.x - 512) << 2) | (t >> 6);
        const int lane = t & 63;
        const int* rowp = adj + (size_t)wid * NN;
        u64 mym = 0;
        for (int g = 0; g < 4; ++g) {
            int v[8];
#pragma unroll
            for (int u = 0; u < 8; ++u)
                v[u] = __builtin_nontemporal_load(rowp + (g * 8 + u) * 64 + lane);
#pragma unroll
            for (int u = 0; u < 8; ++u) {
                u64 m = __ballot(v[u] != 0);
                if (lane == g * 8 + u) mym = m;
            }
        }
        if (lane < 32) abits[(size_t)wid * 32 + lane] = mym;
        return;
    }

    // ---- projection: h = x @ W^T (fp32) ----
    const int b = blockIdx.x >> 7;
    const int n0 = (blockIdx.x & 127) * 16;

    {
        const f32x4* src = (const f32x4*)(x + ((size_t)b * NN + n0) * F_IN);
        f32x4* dst = (f32x4*)&xs[0][0];
        dst[t] = src[t];
        dst[t + 256] = src[t + 256];
    }
    __syncthreads();

    float acc[16];
#pragma unroll
    for (int n = 0; n < 16; ++n) acc[n] = 0.f;

    const float* wrow = W + (size_t)t * F_IN;
#pragma unroll 2
    for (int k0 = 0; k0 < F_IN; k0 += 8) {
        f32x4 w0 = *(const f32x4*)(wrow + k0);
        f32x4 w1 = *(const f32x4*)(wrow + k0 + 4);
#pragma unroll
        for (int n = 0; n < 16; ++n) {
            f32x4 xa = *(const f32x4*)&xs[n][k0];
            f32x4 xb = *(const f32x4*)&xs[n][k0 + 4];
            float s = acc[n];
            s = fmaf(xa[0], w0[0], s); s = fmaf(xa[1], w0[1], s);
            s = fmaf(xa[2], w0[2], s); s = fmaf(xa[3], w0[3], s);
            s = fmaf(xb[0], w1[0], s); s = fmaf(xb[1], w1[1], s);
            s = fmaf(xb[2], w1[2], s); s = fmaf(xb[3], w1[3], s);
            acc[n] = s;
        }
    }
    __syncthreads();   // all xs reads done before red (aliased) is written

    const int w = t >> 6, lane = t & 63;
    const float al = a_l[t];
    const float ar = a_r[t];
    const int n_ = lane & 15, og = lane >> 4;
    float sl, sr;
    // l pass
    {
        float* rp = &red[((size_t)w * 64 + lane) * 20];
#pragma unroll
        for (int q = 0; q < 4; ++q) {
            f32x4 v;
#pragma unroll
            for (int e = 0; e < 4; ++e) v[e] = acc[q * 4 + e] * al;
            *(f32x4*)(rp + q * 4) = v;
        }
    }
    __syncthreads();
    {
        float s = 0.f;
#pragma unroll
        for (int oo = 0; oo < 16; ++oo)
            s += red[((size_t)w * 64 + og + 4 * oo) * 20 + n_];
        s += __shfl_xor(s, 16, 64); s += __shfl_xor(s, 32, 64);
        sl = s;
    }
    __syncthreads();
    // r pass (reuse buffer)
    {
        float* rp = &red[((size_t)w * 64 + lane) * 20];
#pragma unroll
        for (int q = 0; q < 4; ++q) {
            f32x4 v;
#pragma unroll
            for (int e = 0; e < 4; ++e) v[e] = acc[q * 4 + e] * ar;
            *(f32x4*)(rp + q * 4) = v;
        }
    }
    __syncthreads();
    {
        float s = 0.f;
#pragma unroll
        for (int oo = 0; oo < 16; ++oo)
            s += red[((size_t)w * 64 + og + 4 * oo) * 20 + n_];
        s += __shfl_xor(s, 16, 64); s += __shfl_xor(s, 32, 64);
        sr = s;
    }
    if (lane < 16) {
        el[((size_t)b * NH + w) * NN + n0 + lane] = sl * LOG2E;
        float sre = sr * LOG2E;
        f32x2 v2; v2[0] = exp2_fast(sre); v2[1] = exp2_fast(0.2f * sre);
        er12[((size_t)b * NH + w) * NN + n0 + lane] = v2;
    }

    // B-fragment layout store: hB[b][jt32][head][cb][lane64][8] (bf16)
    const int dcol = t & 15, cb = (t >> 4) & 3;
    const int jt32 = n0 >> 5;
    const int lb = dcol + ((n0 >> 3) & 2) * 16;
    u16* hb = hB + ((((size_t)b * 64 + jt32) * 4 + w) * 4 + cb) * 512 + (size_t)lb * 8;
    s16x8 pk0, pk1;
#pragma unroll
    for (int n = 0; n < 8; ++n) pk0[n] = (short)f32_to_bf16_rtn(acc[n]);
#pragma unroll
    for (int n = 0; n < 8; ++n) pk1[n] = (short)f32_to_bf16_rtn(acc[n + 8]);
    *(s16x8*)hb         = pk0;
    *(s16x8*)(hb + 128) = pk1;
}

// K2: fused masked softmax + aggregation.
// XCD-residency swizzle: (b,w) pair pinned to xcd = bw&7 -> each XCD's 64+64
// i-tile blocks re-read a 2 MB hB working set from their OWN L2 (not L3).
// er12+masks staged in LDS; B-frags dist-1 register prefetch; (256,3) no-spill;
// non-temporal out stores keep the write stream from evicting hB.
#define MSTRIDE 68   // mask LDS row stride (u32): 2-way banks (free)

__global__ __launch_bounds__(256, 3) void k2_attn(
    const uint32_t* __restrict__ abits32, const u16* __restrict__ hB,
    const float* __restrict__ el, const f32x2* __restrict__ er12,
    float* __restrict__ out)
{
    __shared__ __align__(16) char smem[33792];   // max(er 16K + mask 8.5K, racc 33K)
    float*    er_lds   = (float*)smem;           // [2048][2] floats
    uint32_t* mask_lds = (uint32_t*)(smem + 16384); // [32][MSTRIDE]
    float*    racc     = (float*)smem;           // alias (after barrier)

    const int t = threadIdx.x;
    const int jq = t >> 6, l = t & 63;
    // XCD-residency swizzle: hardware round-robins blockIdx%8 across XCDs.
    const int o = blockIdx.x;
    const int kblk = o >> 3;                 // 0..127
    const int bw = (o & 7) + 8 * (kblk & 1); // (b,w) pair, pinned to xcd o&7
    const int b = bw >> 2;
    const int w = bw & 3;
    const int i0 = (kblk >> 1) * 32;
    const int r = l & 15;                 // A row / D col
    const int kb = l >> 4;                // k-slice 0..3
    const int ks = kb * 8;
    const int irow0 = i0 + r, irow1 = irow0 + 16;

    // ---- stage er12 (16 KB) + masks (8 KB, padded rows) into LDS ----
    {
        const f32x4* gsrc = (const f32x4*)(er12 + (size_t)(b * NH + w) * NN);
        f32x4* edst = (f32x4*)er_lds;
#pragma unroll
        for (int p = 0; p < 4; ++p) edst[t + p * 256] = gsrc[t + p * 256];
        const i32x4* msrc = (const i32x4*)(abits32 + ((size_t)b * NN + i0) * 64);
        i32x4 mv0 = msrc[t * 2];
        i32x4 mv1 = msrc[t * 2 + 1];
        const int mrow = t >> 3, mc = (t & 7) * 8;
        *(i32x4*)&mask_lds[mrow * MSTRIDE + mc]     = mv0;
        *(i32x4*)&mask_lds[mrow * MSTRIDE + mc + 4] = mv1;
    }

    const u16* hbp = hB + ((((size_t)b * 64 + jq * 16) * 4 + w) * 4) * 512 + (size_t)l * 8;
    const float eli0 = el[((size_t)b * NH + w) * NN + irow0];
    const float eli1 = el[((size_t)b * NH + w) * NN + irow1];
    const float E1i0 = exp2_fast(eli0), E2i0 = exp2_fast(0.2f * eli0);
    const float E1i1 = exp2_fast(eli1), E2i1 = exp2_fast(0.2f * eli1);

    f32x4 a00 = {0.f,0.f,0.f,0.f}, a01 = a00, a02 = a00, a03 = a00, as0 = a00;
    f32x4 a10 = a00, a11 = a00, a12 = a00, a13 = a00, as1 = a00;
    s16x8 ones;
#pragma unroll
    for (int k = 0; k < 8; ++k) ones[k] = (short)0x3F80;   // bf16 1.0

    // prologue: iter-0 B-frags
    s16x8 b0c = *(const s16x8*)(hbp + 0 * 512);
    s16x8 b1c = *(const s16x8*)(hbp + 1 * 512);
    s16x8 b2c = *(const s16x8*)(hbp + 2 * 512);
    s16x8 b3c = *(const s16x8*)(hbp + 3 * 512);
    __syncthreads();   // staging complete

#define MFMA_BF16 __builtin_amdgcn_mfma_f32_16x16x32_bf16
#define BODY(IT, PF)                                                          \
    {                                                                         \
        const int itv = (IT);                                                 \
        const int jb2 = (jq * 512 + itv * 32 + ks) * 2;                       \
        f32x4 e0 = *(const f32x4*)(er_lds + jb2);                             \
        f32x4 e1 = *(const f32x4*)(er_lds + jb2 + 4);                         \
        f32x4 e2 = *(const f32x4*)(er_lds + jb2 + 8);                         \
        f32x4 e3 = *(const f32x4*)(er_lds + jb2 + 12);                        \
        uint32_t w2a = mask_lds[r * MSTRIDE + jq * 16 + itv] >> ks;           \
        uint32_t w2b = mask_lds[(16 + r) * MSTRIDE + jq * 16 + itv] >> ks;    \
        s16x8 b0n, b1n, b2n, b3n;                                             \
        if (PF) {                                                             \
            const u16* hp_ = hbp + (size_t)(itv + 1) * 8192;                  \
            b0n = *(const s16x8*)(hp_ + 0 * 512);                             \
            b1n = *(const s16x8*)(hp_ + 1 * 512);                             \
            b2n = *(const s16x8*)(hp_ + 2 * 512);                             \
            b3n = *(const s16x8*)(hp_ + 3 * 512);                             \
        }                                                                     \
        __builtin_amdgcn_sched_barrier(0);                                    \
        union { s16x8 v; uint32_t u[4]; } afa, afb;                           \
        _Pragma("unroll")                                                     \
        for (int kk = 0; kk < 4; ++kk) {                                      \
            f32x4 ev = (kk == 0) ? e0 : ((kk == 1) ? e1 : ((kk == 2) ? e2 : e3)); \
            float t00 = E1i0 * ev[0], m00 = E2i0 * ev[1];                     \
            float t01 = E1i0 * ev[2], m01 = E2i0 * ev[3];                     \
            float t10 = E1i1 * ev[0], m10 = E2i1 * ev[1];                     \
            float t11 = E1i1 * ev[2], m11 = E2i1 * ev[3];                     \
            float p00 = fmaxf(t00, m00);   /* = (s>=0)?2^s:2^(0.2s) */        \
            float p01 = fmaxf(t01, m01);                                      \
            float p10 = fmaxf(t10, m10);                                      \
            float p11 = fmaxf(t11, m11);                                      \
            union { float f; uint32_t u; } c00, c01, c10, c11;                \
            c00.f = p00; c01.f = p01; c10.f = p10; c11.f = p11;               \
            uint32_t q00 = c00.u & (uint32_t)sbfe1(w2a, 2 * kk);              \
            uint32_t q01 = c01.u & (uint32_t)sbfe1(w2a, 2 * kk + 1);          \
            uint32_t q10 = c10.u & (uint32_t)sbfe1(w2b, 2 * kk);              \
            uint32_t q11 = c11.u & (uint32_t)sbfe1(w2b, 2 * kk + 1);          \
            afa.u[kk] = __builtin_amdgcn_perm(q01, q00, 0x07060302);          \
            afb.u[kk] = __builtin_amdgcn_perm(q11, q10, 0x07060302);          \
        }                                                                     \
        a00 = MFMA_BF16(afa.v, b0c, a00, 0, 0, 0);                            \
        a01 = MFMA_BF16(afa.v, b1c, a01, 0, 0, 0);                            \
        a02 = MFMA_BF16(afa.v, b2c, a02, 0, 0, 0);                            \
        a03 = MFMA_BF16(afa.v, b3c, a03, 0, 0, 0);                            \
        as0 = MFMA_BF16(afa.v, ones, as0, 0, 0, 0);                           \
        a10 = MFMA_BF16(afb.v, b0c, a10, 0, 0, 0);                            \
        a11 = MFMA_BF16(afb.v, b1c, a11, 0, 0, 0);                            \
        a12 = MFMA_BF16(afb.v, b2c, a12, 0, 0, 0);                            \
        a13 = MFMA_BF16(afb.v, b3c, a13, 0, 0, 0);                            \
        as1 = MFMA_BF16(afb.v, ones, as1, 0, 0, 0);                           \
        if (PF) { b0c = b0n; b1c = b1n; b2c = b2n; b3c = b3n; }               \
    }

    for (int g = 0; g < 3; ++g) {
#pragma unroll
        for (int s = 0; s < 4; ++s) BODY(g * 4 + s, 1);
    }
    BODY(12, 1); BODY(13, 1); BODY(14, 1); BODY(15, 0);

    // ---- cross-jq reduce through LDS (racc aliases er/mask region) ----
    __syncthreads();   // all waves done reading er_lds/mask_lds
    if (jq > 0) {
        float* p = &racc[((jq - 1) * 64 + l) * 44];
        *(f32x4*)(p +  0) = a00; *(f32x4*)(p +  4) = a01;
        *(f32x4*)(p +  8) = a02; *(f32x4*)(p + 12) = a03;
        *(f32x4*)(p + 16) = as0;
        *(f32x4*)(p + 20) = a10; *(f32x4*)(p + 24) = a11;
        *(f32x4*)(p + 28) = a12; *(f32x4*)(p + 32) = a13;
        *(f32x4*)(p + 36) = as1;
    }
    __syncthreads();
    if (jq == 0) {
#pragma unroll
        for (int s = 0; s < 3; ++s) {
            const float* p = &racc[(s * 64 + l) * 44];
            a00 += *(const f32x4*)(p +  0); a01 += *(const f32x4*)(p +  4);
            a02 += *(const f32x4*)(p +  8); a03 += *(const f32x4*)(p + 12);
            as0 += *(const f32x4*)(p + 16);
            a10 += *(const f32x4*)(p + 20); a11 += *(const f32x4*)(p + 24);
            a12 += *(const f32x4*)(p + 28); a13 += *(const f32x4*)(p + 32);
            as1 += *(const f32x4*)(p + 36);
        }

        float* op = out + ((size_t)b * NN + i0) * F_OUT + w * HD;
#pragma unroll
        for (int q = 0; q < 4; ++q) {
            const int row0 = kb * 4 + q;
            float inv0 = 1.0f / as0[q];
            __builtin_nontemporal_store(a00[q] * inv0, &op[(size_t)row0 * F_OUT +  0 + r]);
            __builtin_nontemporal_store(a01[q] * inv0, &op[(size_t)row0 * F_OUT + 16 + r]);
            __builtin_nontemporal_store(a02[q] * inv0, &op[(size_t)row0 * F_OUT + 32 + r]);
            __builtin_nontemporal_store(a03[q] * inv0, &op[(size_t)row0 * F_OUT + 48 + r]);
            const int row1 = 16 + kb * 4 + q;
            float inv1 = 1.0f / as1[q];
            __builtin_nontemporal_store(a10[q] * inv1, &op[(size_t)row1 * F_OUT +  0 + r]);
            __builtin_nontemporal_store(a11[q] * inv1, &op[(size_t)row1 * F_OUT + 16 + r]);
            __builtin_nontemporal_store(a12[q] * inv1, &op[(size_t)row1 * F_OUT + 32 + r]);
            __builtin_nontemporal_store(a13[q] * inv1, &op[(size_t)row1 * F_OUT + 48 + r]);
        }
    }
}

extern "C" void kernel_launch(void* const* d_in, const int* in_sizes, int n_in,
                              void* d_out, int out_size, void* d_ws, size_t ws_size,
                              hipStream_t stream) {
    const float* x   = (const float*)d_in[0];
    const int*   adj = (const int*)d_in[1];
    const float* W   = (const float*)d_in[2];
    const float* a_l = (const float*)d_in[3];
    const float* a_r = (const float*)d_in[4];
    float* out = (float*)d_out;

    char* ws = (char*)d_ws;
    u16*   hB    = (u16*)ws;                                   // 4 MB
    u64*   abits = (u64*)(ws + (size_t)BB * F_OUT * NN * 2);   // 2 MB
    float* el    = (float*)(ws + (size_t)BB * F_OUT * NN * 2 + (size_t)BB * NN * 32 * 8);
    f32x2* er12  = (f32x2*)(el + (size_t)BB * NH * NN);

    k01<<<512 + BB * NN / 4, 256, 0, stream>>>(adj, x, W, a_l, a_r, abits, hB, el, er12);
    k2_attn<<<BB * NH * (NN / 32), 256, 0, stream>>>((const uint32_t*)abits, hB, el, er12, out);
}